// Round 2
// baseline (6555.126 us; speedup 1.0000x reference)
//
#include <hip/hip_runtime.h>

#define TM 64
#define TN 64
#define TK 16

// Y[M,N] = (RELU_IN ? relu(X) : X)[M,K] @ W[N,K]^T + bias[N]
template<bool RELU_IN>
__global__ __launch_bounds__(256) void gemm_bias_kernel(
    const float* __restrict__ X,
    const float* __restrict__ W,
    const float* __restrict__ bias,
    float* __restrict__ Y,
    int M, int N, int K)
{
    __shared__ float sX[TK][TM + 1];
    __shared__ float sW[TK][TN + 1];

    const int t  = threadIdx.x;
    const int m0 = blockIdx.y * TM;
    const int n0 = blockIdx.x * TN;

    // staging: thread t loads float4 at row lm, k-offset lk
    const int lm = t >> 2;          // 0..63
    const int lk = (t & 3) << 2;    // 0,4,8,12

    // compute: 4x4 micro-tile
    const int tn  = (t & 15) << 2;  // 0..60
    const int tmr = (t >> 4) << 2;  // 0..60

    float acc[4][4] = {};

    for (int k0 = 0; k0 < K; k0 += TK) {
        float4 xv = make_float4(0.f, 0.f, 0.f, 0.f);
        const int gm = m0 + lm;
        if (gm < M)
            xv = *reinterpret_cast<const float4*>(X + (long long)gm * K + k0 + lk);
        if (RELU_IN) {
            xv.x = fmaxf(xv.x, 0.f); xv.y = fmaxf(xv.y, 0.f);
            xv.z = fmaxf(xv.z, 0.f); xv.w = fmaxf(xv.w, 0.f);
        }
        sX[lk + 0][lm] = xv.x; sX[lk + 1][lm] = xv.y;
        sX[lk + 2][lm] = xv.z; sX[lk + 3][lm] = xv.w;

        // N is a multiple of 64 here, so n0+lm is always in range
        const float4 wv = *reinterpret_cast<const float4*>(W + (long long)(n0 + lm) * K + k0 + lk);
        sW[lk + 0][lm] = wv.x; sW[lk + 1][lm] = wv.y;
        sW[lk + 2][lm] = wv.z; sW[lk + 3][lm] = wv.w;

        __syncthreads();

#pragma unroll
        for (int kk = 0; kk < TK; ++kk) {
            float a[4], b[4];
#pragma unroll
            for (int i = 0; i < 4; ++i) a[i] = sX[kk][tmr + i];
#pragma unroll
            for (int j = 0; j < 4; ++j) b[j] = sW[kk][tn + j];
#pragma unroll
            for (int i = 0; i < 4; ++i)
#pragma unroll
                for (int j = 0; j < 4; ++j)
                    acc[i][j] = fmaf(a[i], b[j], acc[i][j]);
        }
        __syncthreads();
    }

#pragma unroll
    for (int i = 0; i < 4; ++i) {
        const int gm = m0 + tmr + i;
        if (gm < M) {
#pragma unroll
            for (int j = 0; j < 4; ++j) {
                const int gn = n0 + tn + j;
                Y[(long long)gm * N + gn] = acc[i][j] + bias[gn];
            }
        }
    }
}

// out[row[e], :] += val[e] * H[col[e], :]   (one 64-lane wave per edge)
__global__ __launch_bounds__(256) void spmm_atomic_kernel(
    const int* __restrict__ erow,
    const int* __restrict__ ecol,
    const float* __restrict__ eval,
    const float* __restrict__ H,
    float* __restrict__ out,
    int n_edges, int C)
{
    const long long gid = (long long)blockIdx.x * blockDim.x + threadIdx.x;
    const int lane = (int)(gid & 63);
    const long long e = gid >> 6;
    if (e >= n_edges) return;

    const int   r = erow[e];
    const int   c = ecol[e];
    const float v = eval[e];

    const float* src = H   + (long long)c * C;
    float*       dst = out + (long long)r * C;

    for (int ch = lane; ch < C; ch += 64)
        atomicAdd(dst + ch, v * src[ch]);
}

extern "C" void kernel_launch(void* const* d_in, const int* in_sizes, int n_in,
                              void* d_out, int out_size, void* d_ws, size_t ws_size,
                              hipStream_t stream)
{
    const float* x    = (const float*)d_in[0];
    const int*   erow = (const int*)  d_in[1];
    const int*   ecol = (const int*)  d_in[2];
    const float* eval = (const float*)d_in[3];
    const float* W1   = (const float*)d_in[4];
    const float* b1   = (const float*)d_in[5];
    const float* W2   = (const float*)d_in[6];
    const float* b2   = (const float*)d_in[7];
    const float* W3   = (const float*)d_in[8];
    const float* b3   = (const float*)d_in[9];
    float* out = (float*)d_out;

    const int IN_C = 256, HID_C = 256, OUT_C = 64;
    const int n_nodes = in_sizes[0] / IN_C;
    const int n_edges = in_sizes[1];

    // workspace layout (fp32), 2 x n x 256 = 204.8 MB total:
    //   A: GEMM outputs (layers 1,2) and layer-3 GEMM output (first 64 cols worth)
    //   B: SpMM outputs (layers 1,2)
    float* A = (float*)d_ws;
    float* B = A + (size_t)n_nodes * HID_C;

    const dim3 blk(256);
    const dim3 g_h(HID_C / TN, (n_nodes + TM - 1) / TM);
    const dim3 g_o(OUT_C / TN, (n_nodes + TM - 1) / TM);
    const int spmm_blocks = (int)(((long long)n_edges * 64 + 255) / 256);

    // Layer 1: A = x @ W1^T + b1 ; B = spmm(A)
    gemm_bias_kernel<false><<<g_h, blk, 0, stream>>>(x, W1, b1, A, n_nodes, HID_C, IN_C);
    hipMemsetAsync(B, 0, (size_t)n_nodes * HID_C * sizeof(float), stream);
    spmm_atomic_kernel<<<spmm_blocks, blk, 0, stream>>>(erow, ecol, eval, A, B, n_edges, HID_C);

    // Layer 2: A = relu(B) @ W2^T + b2 ; B = spmm(A)
    gemm_bias_kernel<true><<<g_h, blk, 0, stream>>>(B, W2, b2, A, n_nodes, HID_C, HID_C);
    hipMemsetAsync(B, 0, (size_t)n_nodes * HID_C * sizeof(float), stream);
    spmm_atomic_kernel<<<spmm_blocks, blk, 0, stream>>>(erow, ecol, eval, A, B, n_edges, HID_C);

    // Layer 3: A[n,64] = relu(B) @ W3^T + b3 ; out = spmm(A)   (A reused, dead after layer-2 SpMM)
    gemm_bias_kernel<true><<<g_o, blk, 0, stream>>>(B, W3, b3, A, n_nodes, OUT_C, HID_C);
    hipMemsetAsync(out, 0, (size_t)n_nodes * OUT_C * sizeof(float), stream);
    spmm_atomic_kernel<<<spmm_blocks, blk, 0, stream>>>(erow, ecol, eval, A, out, n_edges, OUT_C);
}

// Round 3
// 2158.303 us; speedup vs baseline: 3.0372x; 3.0372x over previous
//
#include <hip/hip_runtime.h>
#include <hip/hip_bf16.h>

#define TM 64
#define TN 64
#define TK 16

// ---------------- CSR build ----------------

__global__ __launch_bounds__(256) void zero_int_kernel(int* __restrict__ p, int n) {
    int i = blockIdx.x * blockDim.x + threadIdx.x;
    if (i < n) p[i] = 0;
}

__global__ __launch_bounds__(256) void hist_kernel(const int* __restrict__ erow,
                                                   int* __restrict__ counts, int n_edges) {
    int e = blockIdx.x * blockDim.x + threadIdx.x;
    if (e < n_edges) atomicAdd(&counts[erow[e]], 1);
}

// single-workgroup exclusive scan over counts[0..n-1] -> row_ptr[0..n], cursor copy
__global__ __launch_bounds__(1024) void scan_kernel(const int* __restrict__ counts,
                                                    int* __restrict__ row_ptr,
                                                    int* __restrict__ cursor, int n) {
    __shared__ int smem[1024];
    __shared__ int carry_s;
    if (threadIdx.x == 0) carry_s = 0;
    __syncthreads();
    for (int base = 0; base < n; base += 1024) {
        int i = base + threadIdx.x;
        int v = (i < n) ? counts[i] : 0;
        smem[threadIdx.x] = v;
        __syncthreads();
        for (int off = 1; off < 1024; off <<= 1) {
            int t = (threadIdx.x >= (unsigned)off) ? smem[threadIdx.x - off] : 0;
            __syncthreads();
            smem[threadIdx.x] += t;
            __syncthreads();
        }
        int excl = smem[threadIdx.x] - v + carry_s;
        if (i < n) { row_ptr[i] = excl; cursor[i] = excl; }
        __syncthreads();
        if (threadIdx.x == 1023) carry_s += smem[1023];
        __syncthreads();
    }
    if (threadIdx.x == 0) row_ptr[n] = carry_s;
}

__global__ __launch_bounds__(256) void scatter_kernel(const int* __restrict__ erow,
                                                      const int* __restrict__ ecol,
                                                      const float* __restrict__ eval,
                                                      int* __restrict__ cursor,
                                                      int* __restrict__ scol,
                                                      float* __restrict__ sval, int n_edges) {
    int e = blockIdx.x * blockDim.x + threadIdx.x;
    if (e < n_edges) {
        int pos = atomicAdd(&cursor[erow[e]], 1);
        scol[pos] = ecol[e];
        sval[pos] = eval[e];
    }
}

// ---------------- GEMM: Y_bf16[M,N] = (relu?)X_f32[M,K] @ W[N,K]^T + b ----------------

template<bool RELU_IN>
__global__ __launch_bounds__(256) void gemm_bias_kernel(
    const float* __restrict__ X,
    const float* __restrict__ W,
    const float* __restrict__ bias,
    __hip_bfloat16* __restrict__ Y,
    int M, int N, int K)
{
    __shared__ float sX[TK][TM + 1];
    __shared__ float sW[TK][TN + 1];

    const int t  = threadIdx.x;
    const int m0 = blockIdx.y * TM;
    const int n0 = blockIdx.x * TN;

    const int lm = t >> 2;
    const int lk = (t & 3) << 2;

    const int tn  = (t & 15) << 2;
    const int tmr = (t >> 4) << 2;

    float acc[4][4] = {};

    for (int k0 = 0; k0 < K; k0 += TK) {
        float4 xv = make_float4(0.f, 0.f, 0.f, 0.f);
        const int gm = m0 + lm;
        if (gm < M)
            xv = *reinterpret_cast<const float4*>(X + (long long)gm * K + k0 + lk);
        if (RELU_IN) {
            xv.x = fmaxf(xv.x, 0.f); xv.y = fmaxf(xv.y, 0.f);
            xv.z = fmaxf(xv.z, 0.f); xv.w = fmaxf(xv.w, 0.f);
        }
        sX[lk + 0][lm] = xv.x; sX[lk + 1][lm] = xv.y;
        sX[lk + 2][lm] = xv.z; sX[lk + 3][lm] = xv.w;

        const float4 wv = *reinterpret_cast<const float4*>(W + (long long)(n0 + lm) * K + k0 + lk);
        sW[lk + 0][lm] = wv.x; sW[lk + 1][lm] = wv.y;
        sW[lk + 2][lm] = wv.z; sW[lk + 3][lm] = wv.w;

        __syncthreads();

#pragma unroll
        for (int kk = 0; kk < TK; ++kk) {
            float a[4], b[4];
#pragma unroll
            for (int i = 0; i < 4; ++i) a[i] = sX[kk][tmr + i];
#pragma unroll
            for (int j = 0; j < 4; ++j) b[j] = sW[kk][tn + j];
#pragma unroll
            for (int i = 0; i < 4; ++i)
#pragma unroll
                for (int j = 0; j < 4; ++j)
                    acc[i][j] = fmaf(a[i], b[j], acc[i][j]);
        }
        __syncthreads();
    }

#pragma unroll
    for (int i = 0; i < 4; ++i) {
        const int gm = m0 + tmr + i;
        if (gm < M) {
            union { ushort4 u; __hip_bfloat16 h[4]; } pk;
#pragma unroll
            for (int j = 0; j < 4; ++j)
                pk.h[j] = __float2bfloat16(acc[i][j] + bias[n0 + tn + j]);
            *reinterpret_cast<ushort4*>(Y + (long long)gm * N + n0 + tn) = pk.u;
        }
    }
}

// ---------------- CSR gather SpMM ----------------

// C=256: one wave per row, lane handles 4 channels (uint2 = 4 bf16 per edge)
__global__ __launch_bounds__(256) void spmm_csr256_kernel(
    const int* __restrict__ row_ptr,
    const int* __restrict__ scol,
    const float* __restrict__ sval,
    const unsigned int* __restrict__ H,   // bf16 pairs; row stride = 128 uints
    float* __restrict__ out, int n_nodes)
{
    const int row = blockIdx.x * 4 + (threadIdx.x >> 6);
    if (row >= n_nodes) return;
    const int lane = threadIdx.x & 63;

    int p = row_ptr[row];
    const int end = row_ptr[row + 1];

    float a0 = 0.f, a1 = 0.f, a2 = 0.f, a3 = 0.f;
    const int cu = lane * 2;

    for (; p < end; ++p) {
        const int   c = scol[p];
        const float v = sval[p];
        const uint2 u = *reinterpret_cast<const uint2*>(H + (size_t)c * 128 + cu);
        union { unsigned int i; float f; } t;
        t.i = u.x << 16;          a0 = fmaf(v, t.f, a0);
        t.i = u.x & 0xffff0000u;  a1 = fmaf(v, t.f, a1);
        t.i = u.y << 16;          a2 = fmaf(v, t.f, a2);
        t.i = u.y & 0xffff0000u;  a3 = fmaf(v, t.f, a3);
    }

    *reinterpret_cast<float4*>(out + (size_t)row * 256 + lane * 4) =
        make_float4(a0, a1, a2, a3);
}

// C=64: one wave per row, lane handles 1 channel
__global__ __launch_bounds__(256) void spmm_csr64_kernel(
    const int* __restrict__ row_ptr,
    const int* __restrict__ scol,
    const float* __restrict__ sval,
    const __hip_bfloat16* __restrict__ H,  // row stride 64
    float* __restrict__ out, int n_nodes)
{
    const int row = blockIdx.x * 4 + (threadIdx.x >> 6);
    if (row >= n_nodes) return;
    const int lane = threadIdx.x & 63;

    int p = row_ptr[row];
    const int end = row_ptr[row + 1];

    float a = 0.f;
    for (; p < end; ++p) {
        const int   c = scol[p];
        const float v = sval[p];
        a = fmaf(v, __bfloat162float(H[(size_t)c * 64 + lane]), a);
    }
    out[(size_t)row * 64 + lane] = a;
}

// ---------------- launch ----------------

extern "C" void kernel_launch(void* const* d_in, const int* in_sizes, int n_in,
                              void* d_out, int out_size, void* d_ws, size_t ws_size,
                              hipStream_t stream)
{
    const float* x    = (const float*)d_in[0];
    const int*   erow = (const int*)  d_in[1];
    const int*   ecol = (const int*)  d_in[2];
    const float* eval = (const float*)d_in[3];
    const float* W1   = (const float*)d_in[4];
    const float* b1   = (const float*)d_in[5];
    const float* W2   = (const float*)d_in[6];
    const float* b2   = (const float*)d_in[7];
    const float* W3   = (const float*)d_in[8];
    const float* b3   = (const float*)d_in[9];
    float* out = (float*)d_out;

    const int IN_C = 256, HID_C = 256, OUT_C = 64;
    const int n_nodes = in_sizes[0] / IN_C;
    const int n_edges = in_sizes[1];

    // workspace layout (~180 MB):
    //   A  : bf16 [n,256]  GEMM outputs / SpMM gather source   (51.2 MB)
    //   B  : f32  [n,256]  SpMM outputs / next GEMM input      (102.4 MB)
    //   scol,sval : CSR-sorted edges                           (25.6 MB)
    //   row_ptr, counts, cursor                                (1.2 MB)
    char* wsp = (char*)d_ws;
    __hip_bfloat16* A = (__hip_bfloat16*)wsp;              wsp += (size_t)n_nodes * HID_C * sizeof(__hip_bfloat16);
    float*          B = (float*)wsp;                       wsp += (size_t)n_nodes * HID_C * sizeof(float);
    int*   scol    = (int*)wsp;                            wsp += (size_t)n_edges * sizeof(int);
    float* sval    = (float*)wsp;                          wsp += (size_t)n_edges * sizeof(float);
    int*   row_ptr = (int*)wsp;                            wsp += (size_t)(n_nodes + 1) * sizeof(int);
    int*   counts  = (int*)wsp;                            wsp += (size_t)n_nodes * sizeof(int);
    int*   cursor  = (int*)wsp;

    const dim3 blk(256);
    const int eb = (n_edges + 255) / 256;
    const int nb = (n_nodes + 255) / 256;
    const int rb = (n_nodes + 3) / 4;   // 4 rows (waves) per block

    // ---- CSR build ----
    zero_int_kernel<<<nb, blk, 0, stream>>>(counts, n_nodes);
    hist_kernel<<<eb, blk, 0, stream>>>(erow, counts, n_edges);
    scan_kernel<<<1, 1024, 0, stream>>>(counts, row_ptr, cursor, n_nodes);
    scatter_kernel<<<eb, blk, 0, stream>>>(erow, ecol, eval, cursor, scol, sval, n_edges);

    const dim3 g_h(HID_C / TN, (n_nodes + TM - 1) / TM);
    const dim3 g_o(OUT_C / TN, (n_nodes + TM - 1) / TM);

    // Layer 1: A = x @ W1^T + b1 ; B = spmm(A)
    gemm_bias_kernel<false><<<g_h, blk, 0, stream>>>(x, W1, b1, A, n_nodes, HID_C, IN_C);
    spmm_csr256_kernel<<<rb, blk, 0, stream>>>(row_ptr, scol, sval,
                                               (const unsigned int*)A, B, n_nodes);

    // Layer 2: A = relu(B) @ W2^T + b2 ; B = spmm(A)
    gemm_bias_kernel<true><<<g_h, blk, 0, stream>>>(B, W2, b2, A, n_nodes, HID_C, HID_C);
    spmm_csr256_kernel<<<rb, blk, 0, stream>>>(row_ptr, scol, sval,
                                               (const unsigned int*)A, B, n_nodes);

    // Layer 3: A[:, :64] = relu(B) @ W3^T + b3 ; out = spmm(A)
    gemm_bias_kernel<true><<<g_o, blk, 0, stream>>>(B, W3, b3, A, n_nodes, OUT_C, HID_C);
    spmm_csr64_kernel<<<rb, blk, 0, stream>>>(row_ptr, scol, sval,
                                              (const __hip_bfloat16*)A, out, n_nodes);
}

// Round 4
// 1396.479 us; speedup vs baseline: 4.6940x; 1.5455x over previous
//
#include <hip/hip_runtime.h>
#include <hip/hip_bf16.h>
#include <type_traits>

typedef short bf16x8 __attribute__((ext_vector_type(8)));
typedef float f32x4 __attribute__((ext_vector_type(4)));

union PkAB { bf16x8 v; __hip_bfloat16 h[8]; };
union PkO  { uint2 u;  __hip_bfloat16 h[4]; };

// ---------------- CSR build ----------------

__global__ __launch_bounds__(256) void zero_int_kernel(int* __restrict__ p, int n) {
    int i = blockIdx.x * blockDim.x + threadIdx.x;
    if (i < n) p[i] = 0;
}

__global__ __launch_bounds__(256) void hist_kernel(const int* __restrict__ erow,
                                                   int* __restrict__ counts, int n_edges) {
    int e = blockIdx.x * blockDim.x + threadIdx.x;
    if (e < n_edges) atomicAdd(&counts[erow[e]], 1);
}

// vectorized single-workgroup exclusive scan: counts (zero-padded to n_pad4) -> row_ptr[0..n], cursor
__global__ __launch_bounds__(1024) void scan_kernel(const int* __restrict__ counts,
                                                    int* __restrict__ row_ptr,
                                                    int* __restrict__ cursor,
                                                    int n, int n_pad4) {
    __shared__ int smem[1024];
    __shared__ int carry_s;
    const int tid = threadIdx.x;
    if (tid == 0) carry_s = 0;
    __syncthreads();
    for (int base = 0; base < n_pad4; base += 4096) {
        const int i = base + tid * 4;
        int4 v = make_int4(0, 0, 0, 0);
        if (i < n_pad4) v = *reinterpret_cast<const int4*>(counts + i);
        const int s = v.x + v.y + v.z + v.w;
        smem[tid] = s;
        __syncthreads();
        for (int off = 1; off < 1024; off <<= 1) {
            int t = (tid >= off) ? smem[tid - off] : 0;
            __syncthreads();
            smem[tid] += t;
            __syncthreads();
        }
        const int incl = smem[tid];
        const int e0 = incl - s + carry_s;
        const int e1 = e0 + v.x;
        const int e2 = e1 + v.y;
        const int e3 = e2 + v.z;
        if (i     < n) { row_ptr[i]     = e0; cursor[i]     = e0; }
        if (i + 1 < n) { row_ptr[i + 1] = e1; cursor[i + 1] = e1; }
        if (i + 2 < n) { row_ptr[i + 2] = e2; cursor[i + 2] = e2; }
        if (i + 3 < n) { row_ptr[i + 3] = e3; cursor[i + 3] = e3; }
        __syncthreads();
        if (tid == 1023) carry_s += incl;
        __syncthreads();
    }
    if (tid == 0) row_ptr[n] = carry_s;
}

__global__ __launch_bounds__(256) void scatter_kernel(const int* __restrict__ erow,
                                                      const int* __restrict__ ecol,
                                                      const float* __restrict__ eval,
                                                      int* __restrict__ cursor,
                                                      int* __restrict__ scol,
                                                      float* __restrict__ sval, int n_edges) {
    int e = blockIdx.x * blockDim.x + threadIdx.x;
    if (e < n_edges) {
        int pos = atomicAdd(&cursor[erow[e]], 1);
        scol[pos] = ecol[e];
        sval[pos] = eval[e];
    }
}

// ---------------- MFMA GEMM: Y_bf16[M,N] = X[M,256] @ W[N,256]^T + b ----------------
// block = 4 waves, tile 128x64 (wave: 64x32). B-frags for full K=256 in registers.

template<typename TIN>
__global__ __launch_bounds__(256) void gemm_mfma_kernel(
    const TIN* __restrict__ X,
    const float* __restrict__ W,
    const float* __restrict__ bias,
    __hip_bfloat16* __restrict__ Y,
    int M, int N)
{
    constexpr int K = 256;
    const int tid  = threadIdx.x;
    const int lane = tid & 63;
    const int w    = tid >> 6;
    const int wm   = w >> 1, wn = w & 1;
    const int quad = lane >> 4;
    const int l16  = lane & 15;
    const int m0   = blockIdx.y * 128 + wm * 64;
    const int n0   = blockIdx.x * 64 + wn * 32;

    // preload B fragments for full K (f32 -> bf16 in-register)
    bf16x8 bfrag[2][8];
#pragma unroll
    for (int nt = 0; nt < 2; ++nt) {
        const float* wp = W + (size_t)(n0 + nt * 16 + l16) * K + quad * 8;
#pragma unroll
        for (int ks = 0; ks < 8; ++ks) {
            const float4 lo = *reinterpret_cast<const float4*>(wp + ks * 32);
            const float4 hi = *reinterpret_cast<const float4*>(wp + ks * 32 + 4);
            PkAB pk;
            pk.h[0] = __float2bfloat16(lo.x); pk.h[1] = __float2bfloat16(lo.y);
            pk.h[2] = __float2bfloat16(lo.z); pk.h[3] = __float2bfloat16(lo.w);
            pk.h[4] = __float2bfloat16(hi.x); pk.h[5] = __float2bfloat16(hi.y);
            pk.h[6] = __float2bfloat16(hi.z); pk.h[7] = __float2bfloat16(hi.w);
            bfrag[nt][ks] = pk.v;
        }
    }

    int mr[4];
#pragma unroll
    for (int mt = 0; mt < 4; ++mt) {
        int r = m0 + mt * 16 + l16;
        mr[mt] = (r < M) ? r : (M - 1);   // clamp: safe read, rows guarded at store
    }

    f32x4 acc[4][2] = {};

#pragma unroll
    for (int ks = 0; ks < 8; ++ks) {
        bf16x8 a[4];
#pragma unroll
        for (int mt = 0; mt < 4; ++mt) {
            if constexpr (std::is_same<TIN, float>::value) {
                const float* ap = X + (size_t)mr[mt] * K + ks * 32 + quad * 8;
                const float4 lo = *reinterpret_cast<const float4*>(ap);
                const float4 hi = *reinterpret_cast<const float4*>(ap + 4);
                PkAB pk;
                pk.h[0] = __float2bfloat16(lo.x); pk.h[1] = __float2bfloat16(lo.y);
                pk.h[2] = __float2bfloat16(lo.z); pk.h[3] = __float2bfloat16(lo.w);
                pk.h[4] = __float2bfloat16(hi.x); pk.h[5] = __float2bfloat16(hi.y);
                pk.h[6] = __float2bfloat16(hi.z); pk.h[7] = __float2bfloat16(hi.w);
                a[mt] = pk.v;
            } else {
                a[mt] = *reinterpret_cast<const bf16x8*>(
                    X + (size_t)mr[mt] * K + ks * 32 + quad * 8);
            }
        }
#pragma unroll
        for (int mt = 0; mt < 4; ++mt)
#pragma unroll
            for (int nt = 0; nt < 2; ++nt)
                acc[mt][nt] = __builtin_amdgcn_mfma_f32_16x16x32_bf16(
                    a[mt], bfrag[nt][ks], acc[mt][nt], 0, 0, 0);
    }

    const float bv0 = bias[n0 + l16];
    const float bv1 = bias[n0 + 16 + l16];
#pragma unroll
    for (int mt = 0; mt < 4; ++mt) {
#pragma unroll
        for (int r = 0; r < 4; ++r) {
            const int row = m0 + mt * 16 + quad * 4 + r;
            if (row < M) {
                Y[(size_t)row * N + n0 + l16]      = __float2bfloat16(acc[mt][0][r] + bv0);
                Y[(size_t)row * N + n0 + 16 + l16] = __float2bfloat16(acc[mt][1][r] + bv1);
            }
        }
    }
}

// ---------------- CSR gather SpMM ----------------

// C=256: one wave per row, lane = 4 channels; 4 edges in flight; bf16 out (+relu)
template<bool RELU>
__global__ __launch_bounds__(256) void spmm_csr256_kernel(
    const int* __restrict__ row_ptr,
    const int* __restrict__ scol,
    const float* __restrict__ sval,
    const unsigned int* __restrict__ H,   // bf16 pairs; row stride 128 uints
    __hip_bfloat16* __restrict__ out,     // row stride 256
    int n_nodes)
{
    const int row = blockIdx.x * 4 + (threadIdx.x >> 6);
    if (row >= n_nodes) return;
    const int lane = threadIdx.x & 63;
    const int cu = lane * 2;

    int p = row_ptr[row];
    const int end = row_ptr[row + 1];

    float a0 = 0.f, a1 = 0.f, a2 = 0.f, a3 = 0.f;
    union { unsigned int i; float f; } t;

#define ACC_EDGE(u, v)                                        \
    t.i = (u).x << 16;          a0 = fmaf((v), t.f, a0);      \
    t.i = (u).x & 0xffff0000u;  a1 = fmaf((v), t.f, a1);      \
    t.i = (u).y << 16;          a2 = fmaf((v), t.f, a2);      \
    t.i = (u).y & 0xffff0000u;  a3 = fmaf((v), t.f, a3);

    for (; p + 3 < end; p += 4) {
        const int   c0 = scol[p],     c1 = scol[p + 1], c2 = scol[p + 2], c3 = scol[p + 3];
        const float v0 = sval[p],     v1 = sval[p + 1], v2 = sval[p + 2], v3 = sval[p + 3];
        const uint2 u0 = *reinterpret_cast<const uint2*>(H + (size_t)c0 * 128 + cu);
        const uint2 u1 = *reinterpret_cast<const uint2*>(H + (size_t)c1 * 128 + cu);
        const uint2 u2 = *reinterpret_cast<const uint2*>(H + (size_t)c2 * 128 + cu);
        const uint2 u3 = *reinterpret_cast<const uint2*>(H + (size_t)c3 * 128 + cu);
        ACC_EDGE(u0, v0) ACC_EDGE(u1, v1) ACC_EDGE(u2, v2) ACC_EDGE(u3, v3)
    }
    for (; p < end; ++p) {
        const int   c = scol[p];
        const float v = sval[p];
        const uint2 u = *reinterpret_cast<const uint2*>(H + (size_t)c * 128 + cu);
        ACC_EDGE(u, v)
    }
#undef ACC_EDGE

    if (RELU) {
        a0 = fmaxf(a0, 0.f); a1 = fmaxf(a1, 0.f);
        a2 = fmaxf(a2, 0.f); a3 = fmaxf(a3, 0.f);
    }
    PkO pk;
    pk.h[0] = __float2bfloat16(a0); pk.h[1] = __float2bfloat16(a1);
    pk.h[2] = __float2bfloat16(a2); pk.h[3] = __float2bfloat16(a3);
    *reinterpret_cast<uint2*>(out + (size_t)row * 256 + lane * 4) = pk.u;
}

// C=64: one wave per row; half-wave per edge (lane = 2 channels); f32 out, no relu
__global__ __launch_bounds__(256) void spmm_csr64_kernel(
    const int* __restrict__ row_ptr,
    const int* __restrict__ scol,
    const float* __restrict__ sval,
    const __hip_bfloat16* __restrict__ H,  // row stride 64
    float* __restrict__ out, int n_nodes)
{
    const int row = blockIdx.x * 4 + (threadIdx.x >> 6);
    if (row >= n_nodes) return;
    const int lane = threadIdx.x & 63;
    const int half = lane >> 5;
    const int sl   = lane & 31;

    const int end = row_ptr[row + 1];
    int p = row_ptr[row] + half;

    float a0 = 0.f, a1 = 0.f;
    union { unsigned int i; float f; } t;

#define ACC_E64(u, v)                                    \
    t.i = (u) << 16;          a0 = fmaf((v), t.f, a0);   \
    t.i = (u) & 0xffff0000u;  a1 = fmaf((v), t.f, a1);

    for (; p + 2 < end; p += 4) {
        const int   c0 = scol[p], c1 = scol[p + 2];
        const float v0 = sval[p], v1 = sval[p + 2];
        const unsigned int u0 = *reinterpret_cast<const unsigned int*>(H + (size_t)c0 * 64 + sl * 2);
        const unsigned int u1 = *reinterpret_cast<const unsigned int*>(H + (size_t)c1 * 64 + sl * 2);
        ACC_E64(u0, v0) ACC_E64(u1, v1)
    }
    if (p < end) {
        const int   c = scol[p];
        const float v = sval[p];
        const unsigned int u = *reinterpret_cast<const unsigned int*>(H + (size_t)c * 64 + sl * 2);
        ACC_E64(u, v)
    }
#undef ACC_E64

    a0 += __shfl_down(a0, 32, 64);
    a1 += __shfl_down(a1, 32, 64);
    if (half == 0)
        *reinterpret_cast<float2*>(out + (size_t)row * 64 + sl * 2) = make_float2(a0, a1);
}

// ---------------- launch ----------------

extern "C" void kernel_launch(void* const* d_in, const int* in_sizes, int n_in,
                              void* d_out, int out_size, void* d_ws, size_t ws_size,
                              hipStream_t stream)
{
    const float* x    = (const float*)d_in[0];
    const int*   erow = (const int*)  d_in[1];
    const int*   ecol = (const int*)  d_in[2];
    const float* eval = (const float*)d_in[3];
    const float* W1   = (const float*)d_in[4];
    const float* b1   = (const float*)d_in[5];
    const float* W2   = (const float*)d_in[6];
    const float* b2   = (const float*)d_in[7];
    const float* W3   = (const float*)d_in[8];
    const float* b3   = (const float*)d_in[9];
    float* out = (float*)d_out;

    const int IN_C = 256, HID_C = 256, OUT_C = 64;
    const int n_nodes = in_sizes[0] / IN_C;
    const int n_edges = in_sizes[1];
    const int n_pad4  = (n_nodes + 3) & ~3;

    // workspace (~128.4 MB): G | H | scol | sval | counts | cursor | row_ptr
    char* wsp = (char*)d_ws;
    __hip_bfloat16* G = (__hip_bfloat16*)wsp;  wsp += (size_t)n_nodes * HID_C * sizeof(__hip_bfloat16);
    __hip_bfloat16* H = (__hip_bfloat16*)wsp;  wsp += (size_t)n_nodes * HID_C * sizeof(__hip_bfloat16);
    int*   scol    = (int*)wsp;                wsp += (size_t)n_edges * sizeof(int);
    float* sval    = (float*)wsp;              wsp += (size_t)n_edges * sizeof(float);
    int*   counts  = (int*)wsp;                wsp += (size_t)n_pad4 * sizeof(int);
    int*   cursor  = (int*)wsp;                wsp += (size_t)n_pad4 * sizeof(int);
    int*   row_ptr = (int*)wsp;

    const dim3 blk(256);
    const int eb = (n_edges + 255) / 256;
    const int zb = (n_pad4 + 255) / 256;
    const int rb = (n_nodes + 3) / 4;          // 4 rows (waves) per block
    const dim3 g_h(HID_C / 64, (n_nodes + 127) / 128);
    const dim3 g_o(OUT_C / 64, (n_nodes + 127) / 128);

    // ---- CSR build ----
    zero_int_kernel<<<zb, blk, 0, stream>>>(counts, n_pad4);
    hist_kernel<<<eb, blk, 0, stream>>>(erow, counts, n_edges);
    scan_kernel<<<1, 1024, 0, stream>>>(counts, row_ptr, cursor, n_nodes, n_pad4);
    scatter_kernel<<<eb, blk, 0, stream>>>(erow, ecol, eval, cursor, scol, sval, n_edges);

    // Layer 1: G = x @ W1^T + b1 ; H = relu(spmm(G))
    gemm_mfma_kernel<float><<<g_h, blk, 0, stream>>>(x, W1, b1, G, n_nodes, HID_C);
    spmm_csr256_kernel<true><<<rb, blk, 0, stream>>>(row_ptr, scol, sval,
                                                     (const unsigned int*)G, H, n_nodes);

    // Layer 2: G = H @ W2^T + b2 ; H = relu(spmm(G))
    gemm_mfma_kernel<__hip_bfloat16><<<g_h, blk, 0, stream>>>(H, W2, b2, G, n_nodes, HID_C);
    spmm_csr256_kernel<true><<<rb, blk, 0, stream>>>(row_ptr, scol, sval,
                                                     (const unsigned int*)G, H, n_nodes);

    // Layer 3: G[:, :64] = H @ W3^T + b3 ; out = spmm(G)
    gemm_mfma_kernel<__hip_bfloat16><<<g_o, blk, 0, stream>>>(H, W3, b3, G, n_nodes, OUT_C);
    spmm_csr64_kernel<<<rb, blk, 0, stream>>>(row_ptr, scol, sval, G, out, n_nodes);
}

// Round 5
// 1379.844 us; speedup vs baseline: 4.7506x; 1.0121x over previous
//
#include <hip/hip_runtime.h>
#include <hip/hip_bf16.h>
#include <type_traits>

typedef short bf16x8 __attribute__((ext_vector_type(8)));
typedef float f32x4 __attribute__((ext_vector_type(4)));

union PkAB { bf16x8 v; __hip_bfloat16 h[8]; };
union PkO  { uint2 u;  __hip_bfloat16 h[4]; };

// ---------------- CSR build ----------------

__global__ __launch_bounds__(256) void zero_int_kernel(int* __restrict__ p, int n) {
    int i = blockIdx.x * blockDim.x + threadIdx.x;
    if (i < n) p[i] = 0;
}

__global__ __launch_bounds__(256) void hist_kernel(const int* __restrict__ erow,
                                                   int* __restrict__ counts, int n_edges) {
    int e = blockIdx.x * blockDim.x + threadIdx.x;
    if (e < n_edges) atomicAdd(&counts[erow[e]], 1);
}

// vectorized single-workgroup exclusive scan: counts (zero-padded to n_pad4) -> row_ptr[0..n], cursor
__global__ __launch_bounds__(1024) void scan_kernel(const int* __restrict__ counts,
                                                    int* __restrict__ row_ptr,
                                                    int* __restrict__ cursor,
                                                    int n, int n_pad4) {
    __shared__ int smem[1024];
    __shared__ int carry_s;
    const int tid = threadIdx.x;
    if (tid == 0) carry_s = 0;
    __syncthreads();
    for (int base = 0; base < n_pad4; base += 4096) {
        const int i = base + tid * 4;
        int4 v = make_int4(0, 0, 0, 0);
        if (i < n_pad4) v = *reinterpret_cast<const int4*>(counts + i);
        const int s = v.x + v.y + v.z + v.w;
        smem[tid] = s;
        __syncthreads();
        for (int off = 1; off < 1024; off <<= 1) {
            int t = (tid >= off) ? smem[tid - off] : 0;
            __syncthreads();
            smem[tid] += t;
            __syncthreads();
        }
        const int incl = smem[tid];
        const int e0 = incl - s + carry_s;
        const int e1 = e0 + v.x;
        const int e2 = e1 + v.y;
        const int e3 = e2 + v.z;
        if (i     < n) { row_ptr[i]     = e0; cursor[i]     = e0; }
        if (i + 1 < n) { row_ptr[i + 1] = e1; cursor[i + 1] = e1; }
        if (i + 2 < n) { row_ptr[i + 2] = e2; cursor[i + 2] = e2; }
        if (i + 3 < n) { row_ptr[i + 3] = e3; cursor[i + 3] = e3; }
        __syncthreads();
        if (tid == 1023) carry_s += incl;
        __syncthreads();
    }
    if (tid == 0) row_ptr[n] = carry_s;
}

// one 8B packed record per edge: {col, val_bits}
__global__ __launch_bounds__(256) void scatter_kernel(const int* __restrict__ erow,
                                                      const int* __restrict__ ecol,
                                                      const float* __restrict__ eval,
                                                      int* __restrict__ cursor,
                                                      uint2* __restrict__ epk, int n_edges) {
    int e = blockIdx.x * blockDim.x + threadIdx.x;
    if (e < n_edges) {
        int pos = atomicAdd(&cursor[erow[e]], 1);
        uint2 rec;
        rec.x = (unsigned)ecol[e];
        rec.y = __float_as_uint(eval[e]);
        epk[pos] = rec;
    }
}

// ---------------- MFMA GEMM: Y_bf16[M,N] = X[M,256] @ W[N,256]^T + b ----------------
// block = 4 waves, tile 128x64 (wave: 64x32). B-frags for full K=256 in registers.
// A-loads software-pipelined; blocks swizzled so same-A blocks share an XCD.

template<typename TIN>
__device__ __forceinline__ void load_a_frag(const TIN* __restrict__ X, const int* mr,
                                            int ks, int quad, bf16x8 a[4]) {
#pragma unroll
    for (int mt = 0; mt < 4; ++mt) {
        if constexpr (std::is_same<TIN, float>::value) {
            const float* ap = X + (size_t)mr[mt] * 256 + ks * 32 + quad * 8;
            const float4 lo = *reinterpret_cast<const float4*>(ap);
            const float4 hi = *reinterpret_cast<const float4*>(ap + 4);
            PkAB pk;
            pk.h[0] = __float2bfloat16(lo.x); pk.h[1] = __float2bfloat16(lo.y);
            pk.h[2] = __float2bfloat16(lo.z); pk.h[3] = __float2bfloat16(lo.w);
            pk.h[4] = __float2bfloat16(hi.x); pk.h[5] = __float2bfloat16(hi.y);
            pk.h[6] = __float2bfloat16(hi.z); pk.h[7] = __float2bfloat16(hi.w);
            a[mt] = pk.v;
        } else {
            a[mt] = *reinterpret_cast<const bf16x8*>(
                X + (size_t)mr[mt] * 256 + ks * 32 + quad * 8);
        }
    }
}

template<typename TIN>
__global__ __launch_bounds__(256) void gemm_mfma_kernel(
    const TIN* __restrict__ X,
    const float* __restrict__ W,
    const float* __restrict__ bias,
    __hip_bfloat16* __restrict__ Y,
    int M, int N)
{
    constexpr int K = 256;
    const int tid  = threadIdx.x;
    const int lane = tid & 63;
    const int w    = tid >> 6;
    const int wm   = w >> 1, wn = w & 1;
    const int quad = lane >> 4;
    const int l16  = lane & 15;

    // XCD swizzle: put the gridDim.x blocks sharing one A-tile on one XCD.
    // groups of gridDim.x*8 blocks: 8 distinct y-tiles x all x-tiles; dispatch
    // index % 8 (XCD round-robin) equals the y-offset within the group.
    const int gx = gridDim.x, gy = gridDim.y;
    const int i = blockIdx.y * gx + blockIdx.x;
    const int gsz = gx * 8;
    int bx, by;
    if (i < (gx * gy / gsz) * gsz) {
        const int g = i / gsz, r = i % gsz;
        by = g * 8 + (r & 7);
        bx = r >> 3;
    } else {
        by = blockIdx.y; bx = blockIdx.x;
    }

    const int m0 = by * 128 + wm * 64;
    const int n0 = bx * 64 + wn * 32;

    // preload B fragments for full K (f32 -> bf16 in-register)
    bf16x8 bfrag[2][8];
#pragma unroll
    for (int nt = 0; nt < 2; ++nt) {
        const float* wp = W + (size_t)(n0 + nt * 16 + l16) * K + quad * 8;
#pragma unroll
        for (int ks = 0; ks < 8; ++ks) {
            const float4 lo = *reinterpret_cast<const float4*>(wp + ks * 32);
            const float4 hi = *reinterpret_cast<const float4*>(wp + ks * 32 + 4);
            PkAB pk;
            pk.h[0] = __float2bfloat16(lo.x); pk.h[1] = __float2bfloat16(lo.y);
            pk.h[2] = __float2bfloat16(lo.z); pk.h[3] = __float2bfloat16(lo.w);
            pk.h[4] = __float2bfloat16(hi.x); pk.h[5] = __float2bfloat16(hi.y);
            pk.h[6] = __float2bfloat16(hi.z); pk.h[7] = __float2bfloat16(hi.w);
            bfrag[nt][ks] = pk.v;
        }
    }

    int mr[4];
#pragma unroll
    for (int mt = 0; mt < 4; ++mt) {
        int r = m0 + mt * 16 + l16;
        mr[mt] = (r < M) ? r : (M - 1);   // clamp: safe read, rows guarded at store
    }

    f32x4 acc[4][2] = {};

    bf16x8 a_cur[4];
    load_a_frag(X, mr, 0, quad, a_cur);

#pragma unroll
    for (int ks = 0; ks < 8; ++ks) {
        bf16x8 a_nxt[4];
        if (ks < 7) load_a_frag(X, mr, ks + 1, quad, a_nxt);
#pragma unroll
        for (int mt = 0; mt < 4; ++mt)
#pragma unroll
            for (int nt = 0; nt < 2; ++nt)
                acc[mt][nt] = __builtin_amdgcn_mfma_f32_16x16x32_bf16(
                    a_cur[mt], bfrag[nt][ks], acc[mt][nt], 0, 0, 0);
#pragma unroll
        for (int mt = 0; mt < 4; ++mt) a_cur[mt] = a_nxt[mt];
    }

    const float bv0 = bias[n0 + l16];
    const float bv1 = bias[n0 + 16 + l16];
#pragma unroll
    for (int mt = 0; mt < 4; ++mt) {
#pragma unroll
        for (int r = 0; r < 4; ++r) {
            const int row = m0 + mt * 16 + quad * 4 + r;
            if (row < M) {
                Y[(size_t)row * N + n0 + l16]      = __float2bfloat16(acc[mt][0][r] + bv0);
                Y[(size_t)row * N + n0 + 16 + l16] = __float2bfloat16(acc[mt][1][r] + bv1);
            }
        }
    }
}

// ---------------- CSR gather SpMM ----------------

// C=256: one wave per row, lane = 4 channels; 8 edges in flight; bf16 out (+relu)
template<bool RELU>
__global__ __launch_bounds__(256) void spmm_csr256_kernel(
    const int* __restrict__ row_ptr,
    const uint2* __restrict__ epk,        // packed {col, val_bits}
    const unsigned int* __restrict__ H,   // bf16 pairs; row stride 128 uints
    __hip_bfloat16* __restrict__ out,     // row stride 256
    int n_nodes)
{
    const int row = blockIdx.x * 4 + (threadIdx.x >> 6);
    if (row >= n_nodes) return;
    const int lane = threadIdx.x & 63;
    const int cu = lane * 2;

    int p = row_ptr[row];
    const int end = row_ptr[row + 1];

    float a0 = 0.f, a1 = 0.f, a2 = 0.f, a3 = 0.f;
    union { unsigned int i; float f; } t;

#define ACC_EDGE(u, v)                                        \
    t.i = (u).x << 16;          a0 = fmaf((v), t.f, a0);      \
    t.i = (u).x & 0xffff0000u;  a1 = fmaf((v), t.f, a1);      \
    t.i = (u).y << 16;          a2 = fmaf((v), t.f, a2);      \
    t.i = (u).y & 0xffff0000u;  a3 = fmaf((v), t.f, a3);

    for (; p + 7 < end; p += 8) {
        uint2 r[8];
#pragma unroll
        for (int j = 0; j < 8; ++j) r[j] = epk[p + j];
        uint2 u[8];
#pragma unroll
        for (int j = 0; j < 8; ++j)
            u[j] = *reinterpret_cast<const uint2*>(H + (size_t)r[j].x * 128 + cu);
#pragma unroll
        for (int j = 0; j < 8; ++j) { ACC_EDGE(u[j], __uint_as_float(r[j].y)) }
    }
    for (; p < end; ++p) {
        const uint2 r = epk[p];
        const uint2 u = *reinterpret_cast<const uint2*>(H + (size_t)r.x * 128 + cu);
        ACC_EDGE(u, __uint_as_float(r.y))
    }
#undef ACC_EDGE

    if (RELU) {
        a0 = fmaxf(a0, 0.f); a1 = fmaxf(a1, 0.f);
        a2 = fmaxf(a2, 0.f); a3 = fmaxf(a3, 0.f);
    }
    PkO pk;
    pk.h[0] = __float2bfloat16(a0); pk.h[1] = __float2bfloat16(a1);
    pk.h[2] = __float2bfloat16(a2); pk.h[3] = __float2bfloat16(a3);
    *reinterpret_cast<uint2*>(out + (size_t)row * 256 + lane * 4) = pk.u;
}

// C=64: one wave per row; half-wave per edge (lane = 2 channels); f32 out, no relu
__global__ __launch_bounds__(256) void spmm_csr64_kernel(
    const int* __restrict__ row_ptr,
    const uint2* __restrict__ epk,
    const __hip_bfloat16* __restrict__ H,  // row stride 64
    float* __restrict__ out, int n_nodes)
{
    const int row = blockIdx.x * 4 + (threadIdx.x >> 6);
    if (row >= n_nodes) return;
    const int lane = threadIdx.x & 63;
    const int half = lane >> 5;
    const int sl   = lane & 31;

    const int end = row_ptr[row + 1];
    int p = row_ptr[row] + half;

    float a0 = 0.f, a1 = 0.f;
    union { unsigned int i; float f; } t;

#define ACC_E64(u, v)                                    \
    t.i = (u) << 16;          a0 = fmaf((v), t.f, a0);   \
    t.i = (u) & 0xffff0000u;  a1 = fmaf((v), t.f, a1);

    for (; p + 6 < end; p += 8) {   // this half handles p, p+2, p+4, p+6
        uint2 r[4];
#pragma unroll
        for (int j = 0; j < 4; ++j) r[j] = epk[p + 2 * j];
        unsigned int u[4];
#pragma unroll
        for (int j = 0; j < 4; ++j)
            u[j] = *reinterpret_cast<const unsigned int*>(H + (size_t)r[j].x * 64 + sl * 2);
#pragma unroll
        for (int j = 0; j < 4; ++j) { ACC_E64(u[j], __uint_as_float(r[j].y)) }
    }
    for (; p < end; p += 2) {
        const uint2 r = epk[p];
        const unsigned int u = *reinterpret_cast<const unsigned int*>(H + (size_t)r.x * 64 + sl * 2);
        ACC_E64(u, __uint_as_float(r.y))
    }
#undef ACC_E64

    a0 += __shfl_down(a0, 32, 64);
    a1 += __shfl_down(a1, 32, 64);
    if (half == 0)
        *reinterpret_cast<float2*>(out + (size_t)row * 64 + sl * 2) = make_float2(a0, a1);
}

// ---------------- launch ----------------

extern "C" void kernel_launch(void* const* d_in, const int* in_sizes, int n_in,
                              void* d_out, int out_size, void* d_ws, size_t ws_size,
                              hipStream_t stream)
{
    const float* x    = (const float*)d_in[0];
    const int*   erow = (const int*)  d_in[1];
    const int*   ecol = (const int*)  d_in[2];
    const float* eval = (const float*)d_in[3];
    const float* W1   = (const float*)d_in[4];
    const float* b1   = (const float*)d_in[5];
    const float* W2   = (const float*)d_in[6];
    const float* b2   = (const float*)d_in[7];
    const float* W3   = (const float*)d_in[8];
    const float* b3   = (const float*)d_in[9];
    float* out = (float*)d_out;

    const int IN_C = 256, HID_C = 256, OUT_C = 64;
    const int n_nodes = in_sizes[0] / IN_C;
    const int n_edges = in_sizes[1];
    const int n_pad4  = (n_nodes + 3) & ~3;

    // workspace (~128.4 MB): G | H | epk | counts | cursor | row_ptr
    char* wsp = (char*)d_ws;
    __hip_bfloat16* G = (__hip_bfloat16*)wsp;  wsp += (size_t)n_nodes * HID_C * sizeof(__hip_bfloat16);
    __hip_bfloat16* H = (__hip_bfloat16*)wsp;  wsp += (size_t)n_nodes * HID_C * sizeof(__hip_bfloat16);
    uint2* epk     = (uint2*)wsp;              wsp += (size_t)n_edges * sizeof(uint2);
    int*   counts  = (int*)wsp;                wsp += (size_t)n_pad4 * sizeof(int);
    int*   cursor  = (int*)wsp;                wsp += (size_t)n_pad4 * sizeof(int);
    int*   row_ptr = (int*)wsp;

    const dim3 blk(256);
    const int eb = (n_edges + 255) / 256;
    const int zb = (n_pad4 + 255) / 256;
    const int rb = (n_nodes + 3) / 4;          // 4 rows (waves) per block
    const dim3 g_h(HID_C / 64, (n_nodes + 127) / 128);
    const dim3 g_o(OUT_C / 64, (n_nodes + 127) / 128);

    // ---- CSR build ----
    zero_int_kernel<<<zb, blk, 0, stream>>>(counts, n_pad4);
    hist_kernel<<<eb, blk, 0, stream>>>(erow, counts, n_edges);
    scan_kernel<<<1, 1024, 0, stream>>>(counts, row_ptr, cursor, n_nodes, n_pad4);
    scatter_kernel<<<eb, blk, 0, stream>>>(erow, ecol, eval, cursor, epk, n_edges);

    // Layer 1: G = x @ W1^T + b1 ; H = relu(spmm(G))
    gemm_mfma_kernel<float><<<g_h, blk, 0, stream>>>(x, W1, b1, G, n_nodes, HID_C);
    spmm_csr256_kernel<true><<<rb, blk, 0, stream>>>(row_ptr, epk,
                                                     (const unsigned int*)G, H, n_nodes);

    // Layer 2: G = H @ W2^T + b2 ; H = relu(spmm(G))
    gemm_mfma_kernel<__hip_bfloat16><<<g_h, blk, 0, stream>>>(H, W2, b2, G, n_nodes, HID_C);
    spmm_csr256_kernel<true><<<rb, blk, 0, stream>>>(row_ptr, epk,
                                                     (const unsigned int*)G, H, n_nodes);

    // Layer 3: G[:, :64] = H @ W3^T + b3 ; out = spmm(G)
    gemm_mfma_kernel<__hip_bfloat16><<<g_o, blk, 0, stream>>>(H, W3, b3, G, n_nodes, OUT_C);
    spmm_csr64_kernel<<<rb, blk, 0, stream>>>(row_ptr, epk, G, out, n_nodes);
}

// Round 6
// 1282.935 us; speedup vs baseline: 5.1095x; 1.0755x over previous
//
#include <hip/hip_runtime.h>
#include <hip/hip_bf16.h>
#include <type_traits>

typedef short bf16x8 __attribute__((ext_vector_type(8)));
typedef float f32x4 __attribute__((ext_vector_type(4)));

union PkAB { bf16x8 v; __hip_bfloat16 h[8]; };
union PkO  { uint2 u;  __hip_bfloat16 h[4]; };

#define NB_MAX 128      // max row-buckets (bucket = row >> 10)
#define EPB    2048     // edges per block in binning kernels

// ---------------- small utility kernels ----------------

__global__ __launch_bounds__(256) void zero_int_kernel(int* __restrict__ p, int n) {
    int i = blockIdx.x * blockDim.x + threadIdx.x;
    if (i < n) p[i] = 0;
}

// convert W1|W2|W3 (f32) to one contiguous bf16 array
__global__ __launch_bounds__(256) void convw_kernel(
    const float* __restrict__ W1, const float* __restrict__ W2,
    const float* __restrict__ W3, __hip_bfloat16* __restrict__ Wb,
    int n1, int n2, int n3)
{
    int i = (blockIdx.x * blockDim.x + threadIdx.x) * 4;
    if (i >= n1 + n2 + n3) return;
    const float* src; int off;
    if (i < n1)           { src = W1; off = i; }
    else if (i < n1 + n2) { src = W2; off = i - n1; }
    else                  { src = W3; off = i - n1 - n2; }
    const float4 v = *reinterpret_cast<const float4*>(src + off);
    PkO pk;
    pk.h[0] = __float2bfloat16(v.x); pk.h[1] = __float2bfloat16(v.y);
    pk.h[2] = __float2bfloat16(v.z); pk.h[3] = __float2bfloat16(v.w);
    *reinterpret_cast<uint2*>(Wb + i) = pk.u;
}

// ---------------- CSR build (binned two-pass) ----------------

// fused row histogram + bucket histogram (LDS-aggregated)
__global__ __launch_bounds__(256) void hist2_kernel(
    const int* __restrict__ erow, int* __restrict__ counts,
    int* __restrict__ bcnt, int n_edges, int nb)
{
    __shared__ int lb[NB_MAX];
    const int tid = threadIdx.x;
    if (tid < NB_MAX) lb[tid] = 0;
    __syncthreads();
    const int e0 = blockIdx.x * EPB;
#pragma unroll
    for (int k = 0; k < 8; ++k) {
        const int e = e0 + tid + k * 256;
        if (e < n_edges) {
            const int r = erow[e];
            atomicAdd(&counts[r], 1);
            atomicAdd(&lb[r >> 10], 1);
        }
    }
    __syncthreads();
    if (tid < nb && lb[tid]) atomicAdd(&bcnt[tid], lb[tid]);
}

// single-block scan: buckets -> gcursor ; rows -> row_ptr + cursor
__global__ __launch_bounds__(1024) void scan_kernel(
    const int* __restrict__ counts, const int* __restrict__ bcnt,
    int* __restrict__ row_ptr, int* __restrict__ cursor,
    int* __restrict__ gcursor, int n, int n_pad4, int nb)
{
    __shared__ int smem[1024];
    __shared__ int sb[NB_MAX];
    __shared__ int carry_s;
    const int tid = threadIdx.x;

    // bucket exclusive scan (small, serial in LDS)
    if (tid < nb) sb[tid] = bcnt[tid];
    if (tid == 0) carry_s = 0;
    __syncthreads();
    if (tid == 0) {
        int run = 0;
        for (int b = 0; b < nb; ++b) { const int t = sb[b]; sb[b] = run; run += t; }
    }
    __syncthreads();
    if (tid < nb) gcursor[tid] = sb[tid];
    __syncthreads();

    // row exclusive scan
    for (int base = 0; base < n_pad4; base += 4096) {
        const int i = base + tid * 4;
        int4 v = make_int4(0, 0, 0, 0);
        if (i < n_pad4) v = *reinterpret_cast<const int4*>(counts + i);
        const int s = v.x + v.y + v.z + v.w;
        smem[tid] = s;
        __syncthreads();
        for (int off = 1; off < 1024; off <<= 1) {
            int t = (tid >= off) ? smem[tid - off] : 0;
            __syncthreads();
            smem[tid] += t;
            __syncthreads();
        }
        const int incl = smem[tid];
        const int e0 = incl - s + carry_s;
        const int e1 = e0 + v.x;
        const int e2 = e1 + v.y;
        const int e3 = e2 + v.z;
        if (i     < n) { row_ptr[i]     = e0; cursor[i]     = e0; }
        if (i + 1 < n) { row_ptr[i + 1] = e1; cursor[i + 1] = e1; }
        if (i + 2 < n) { row_ptr[i + 2] = e2; cursor[i + 2] = e2; }
        if (i + 3 < n) { row_ptr[i + 3] = e3; cursor[i + 3] = e3; }
        __syncthreads();
        if (tid == 1023) carry_s += incl;
        __syncthreads();
    }
    if (tid == 0) row_ptr[n] = carry_s;
}

// pass A: bucket-bin edges; per-block contiguous range per bucket -> write-combinable
__global__ __launch_bounds__(256) void bin_pass_a(
    const int* __restrict__ erow, const int* __restrict__ ecol,
    const float* __restrict__ eval, int* __restrict__ gcursor,
    int* __restrict__ srow, uint2* __restrict__ epk8, int n_edges, int nb)
{
    __shared__ int cnt[NB_MAX];
    __shared__ int base_s[NB_MAX];
    __shared__ int lcur[NB_MAX];
    const int tid = threadIdx.x;
    if (tid < NB_MAX) { cnt[tid] = 0; lcur[tid] = 0; }
    __syncthreads();
    const int e0 = blockIdx.x * EPB;
    int r[8];
#pragma unroll
    for (int k = 0; k < 8; ++k) {
        const int e = e0 + tid + k * 256;
        r[k] = -1;
        if (e < n_edges) { r[k] = erow[e]; atomicAdd(&cnt[r[k] >> 10], 1); }
    }
    __syncthreads();
    if (tid < nb && cnt[tid] > 0) base_s[tid] = atomicAdd(&gcursor[tid], cnt[tid]);
    __syncthreads();
#pragma unroll
    for (int k = 0; k < 8; ++k) {
        const int e = e0 + tid + k * 256;
        if (e < n_edges) {
            const int b = r[k] >> 10;
            const int pos = base_s[b] + atomicAdd(&lcur[b], 1);
            srow[pos] = r[k];
            uint2 rec;
            rec.x = (unsigned)ecol[e];
            rec.y = __float_as_uint(eval[e]);
            epk8[pos] = rec;
        }
    }
}

// pass B: within-bucket scatter to final CSR order (randomness confined to L2-sized region)
__global__ __launch_bounds__(256) void bin_pass_b(
    const int* __restrict__ srow, const uint2* __restrict__ epk8,
    int* __restrict__ cursor, uint2* __restrict__ epk, int n_edges)
{
    const int i = blockIdx.x * blockDim.x + threadIdx.x;
    if (i < n_edges) {
        const int r = srow[i];
        const int pos = atomicAdd(&cursor[r], 1);
        epk[pos] = epk8[i];
    }
}

// ---------------- MFMA GEMM: Y_bf16[M,N] = X[M,256] @ Wb[N,256]^T + b ----------------
// wave tile 64x64 (mt=4, nt=4). N==256: 4 waves span all cols (X read once, no
// cross-block A sharing). N==64: waves stack in M. A and B double-buffer-streamed.

template<typename TIN>
__device__ __forceinline__ bf16x8 load_frag(const TIN* __restrict__ p) {
    if constexpr (std::is_same<TIN, float>::value) {
        const float4 lo = *reinterpret_cast<const float4*>(p);
        const float4 hi = *reinterpret_cast<const float4*>(p + 4);
        PkAB pk;
        pk.h[0] = __float2bfloat16(lo.x); pk.h[1] = __float2bfloat16(lo.y);
        pk.h[2] = __float2bfloat16(lo.z); pk.h[3] = __float2bfloat16(lo.w);
        pk.h[4] = __float2bfloat16(hi.x); pk.h[5] = __float2bfloat16(hi.y);
        pk.h[6] = __float2bfloat16(hi.z); pk.h[7] = __float2bfloat16(hi.w);
        return pk.v;
    } else {
        return *reinterpret_cast<const bf16x8*>(p);
    }
}

template<typename TIN>
__global__ __launch_bounds__(256) void gemm_mfma_kernel(
    const TIN* __restrict__ X,
    const __hip_bfloat16* __restrict__ Wb,   // [N,256] bf16
    const float* __restrict__ bias,
    __hip_bfloat16* __restrict__ Y,
    int M, int N)
{
    constexpr int K = 256;
    const int tid  = threadIdx.x;
    const int lane = tid & 63;
    const int w    = tid >> 6;
    const int quad = lane >> 4;
    const int l16  = lane & 15;
    const bool wide = (N == 256);
    const int m0 = blockIdx.x * (wide ? 64 : 256) + (wide ? 0 : w * 64);
    const int n0 = wide ? w * 64 : 0;

    int mr[4];
#pragma unroll
    for (int mt = 0; mt < 4; ++mt) {
        const int r = m0 + mt * 16 + l16;
        mr[mt] = (r < M) ? r : (M - 1);   // clamped read; store guarded
    }
    const __hip_bfloat16* wp = Wb + (size_t)(n0 + l16) * K + quad * 8;

    f32x4 acc[4][4] = {};
    bf16x8 a_cur[4], b_cur[4];
#pragma unroll
    for (int mt = 0; mt < 4; ++mt)
        a_cur[mt] = load_frag(X + (size_t)mr[mt] * K + quad * 8);
#pragma unroll
    for (int nt = 0; nt < 4; ++nt)
        b_cur[nt] = *reinterpret_cast<const bf16x8*>(wp + nt * 16 * K);

#pragma unroll
    for (int ks = 0; ks < 8; ++ks) {
        bf16x8 a_nxt[4], b_nxt[4];
        if (ks < 7) {
            const int ko = (ks + 1) * 32 + quad * 8;
#pragma unroll
            for (int mt = 0; mt < 4; ++mt)
                a_nxt[mt] = load_frag(X + (size_t)mr[mt] * K + ko);
#pragma unroll
            for (int nt = 0; nt < 4; ++nt)
                b_nxt[nt] = *reinterpret_cast<const bf16x8*>(wp + nt * 16 * K + (ks + 1) * 32);
        }
#pragma unroll
        for (int mt = 0; mt < 4; ++mt)
#pragma unroll
            for (int nt = 0; nt < 4; ++nt)
                acc[mt][nt] = __builtin_amdgcn_mfma_f32_16x16x32_bf16(
                    a_cur[mt], b_cur[nt], acc[mt][nt], 0, 0, 0);
        if (ks < 7) {
#pragma unroll
            for (int mt = 0; mt < 4; ++mt) a_cur[mt] = a_nxt[mt];
#pragma unroll
            for (int nt = 0; nt < 4; ++nt) b_cur[nt] = b_nxt[nt];
        }
    }

    float bv[4];
#pragma unroll
    for (int nt = 0; nt < 4; ++nt) bv[nt] = bias[n0 + nt * 16 + l16];
#pragma unroll
    for (int mt = 0; mt < 4; ++mt)
#pragma unroll
        for (int r = 0; r < 4; ++r) {
            const int row = m0 + mt * 16 + quad * 4 + r;
            if (row < M) {
#pragma unroll
                for (int nt = 0; nt < 4; ++nt)
                    Y[(size_t)row * N + n0 + nt * 16 + l16] =
                        __float2bfloat16(acc[mt][nt][r] + bv[nt]);
            }
        }
}

// ---------------- CSR gather SpMM ----------------

// C=256: one wave per row, lane = 4 channels; 8 edges in flight; bf16 out (+relu)
template<bool RELU>
__global__ __launch_bounds__(256) void spmm_csr256_kernel(
    const int* __restrict__ row_ptr,
    const uint2* __restrict__ epk,        // packed {col, val_bits}
    const unsigned int* __restrict__ H,   // bf16 pairs; row stride 128 uints
    __hip_bfloat16* __restrict__ out,     // row stride 256
    int n_nodes)
{
    const int row = blockIdx.x * 4 + (threadIdx.x >> 6);
    if (row >= n_nodes) return;
    const int lane = threadIdx.x & 63;
    const int cu = lane * 2;

    int p = row_ptr[row];
    const int end = row_ptr[row + 1];

    float a0 = 0.f, a1 = 0.f, a2 = 0.f, a3 = 0.f;
    union { unsigned int i; float f; } t;

#define ACC_EDGE(u, v)                                        \
    t.i = (u).x << 16;          a0 = fmaf((v), t.f, a0);      \
    t.i = (u).x & 0xffff0000u;  a1 = fmaf((v), t.f, a1);      \
    t.i = (u).y << 16;          a2 = fmaf((v), t.f, a2);      \
    t.i = (u).y & 0xffff0000u;  a3 = fmaf((v), t.f, a3);

    for (; p + 7 < end; p += 8) {
        uint2 r[8];
#pragma unroll
        for (int j = 0; j < 8; ++j) r[j] = epk[p + j];
        uint2 u[8];
#pragma unroll
        for (int j = 0; j < 8; ++j)
            u[j] = *reinterpret_cast<const uint2*>(H + (size_t)r[j].x * 128 + cu);
#pragma unroll
        for (int j = 0; j < 8; ++j) { ACC_EDGE(u[j], __uint_as_float(r[j].y)) }
    }
    for (; p < end; ++p) {
        const uint2 r = epk[p];
        const uint2 u = *reinterpret_cast<const uint2*>(H + (size_t)r.x * 128 + cu);
        ACC_EDGE(u, __uint_as_float(r.y))
    }
#undef ACC_EDGE

    if (RELU) {
        a0 = fmaxf(a0, 0.f); a1 = fmaxf(a1, 0.f);
        a2 = fmaxf(a2, 0.f); a3 = fmaxf(a3, 0.f);
    }
    PkO pk;
    pk.h[0] = __float2bfloat16(a0); pk.h[1] = __float2bfloat16(a1);
    pk.h[2] = __float2bfloat16(a2); pk.h[3] = __float2bfloat16(a3);
    *reinterpret_cast<uint2*>(out + (size_t)row * 256 + lane * 4) = pk.u;
}

// C=64: one wave per row; half-wave per edge (lane = 2 channels); f32 out
__global__ __launch_bounds__(256) void spmm_csr64_kernel(
    const int* __restrict__ row_ptr,
    const uint2* __restrict__ epk,
    const __hip_bfloat16* __restrict__ H,  // row stride 64
    float* __restrict__ out, int n_nodes)
{
    const int row = blockIdx.x * 4 + (threadIdx.x >> 6);
    if (row >= n_nodes) return;
    const int lane = threadIdx.x & 63;
    const int half = lane >> 5;
    const int sl   = lane & 31;

    const int end = row_ptr[row + 1];
    int p = row_ptr[row] + half;

    float a0 = 0.f, a1 = 0.f;
    union { unsigned int i; float f; } t;

#define ACC_E64(u, v)                                    \
    t.i = (u) << 16;          a0 = fmaf((v), t.f, a0);   \
    t.i = (u) & 0xffff0000u;  a1 = fmaf((v), t.f, a1);

    for (; p + 6 < end; p += 8) {   // this half handles p, p+2, p+4, p+6
        uint2 r[4];
#pragma unroll
        for (int j = 0; j < 4; ++j) r[j] = epk[p + 2 * j];
        unsigned int u[4];
#pragma unroll
        for (int j = 0; j < 4; ++j)
            u[j] = *reinterpret_cast<const unsigned int*>(H + (size_t)r[j].x * 64 + sl * 2);
#pragma unroll
        for (int j = 0; j < 4; ++j) { ACC_E64(u[j], __uint_as_float(r[j].y)) }
    }
    for (; p < end; p += 2) {
        const uint2 r = epk[p];
        const unsigned int u = *reinterpret_cast<const unsigned int*>(H + (size_t)r.x * 64 + sl * 2);
        ACC_E64(u, __uint_as_float(r.y))
    }
#undef ACC_E64

    a0 += __shfl_down(a0, 32, 64);
    a1 += __shfl_down(a1, 32, 64);
    if (half == 0)
        *reinterpret_cast<float2*>(out + (size_t)row * 64 + sl * 2) = make_float2(a0, a1);
}

// ---------------- launch ----------------

extern "C" void kernel_launch(void* const* d_in, const int* in_sizes, int n_in,
                              void* d_out, int out_size, void* d_ws, size_t ws_size,
                              hipStream_t stream)
{
    const float* x    = (const float*)d_in[0];
    const int*   erow = (const int*)  d_in[1];
    const int*   ecol = (const int*)  d_in[2];
    const float* eval = (const float*)d_in[3];
    const float* W1   = (const float*)d_in[4];
    const float* b1   = (const float*)d_in[5];
    const float* W2   = (const float*)d_in[6];
    const float* b2   = (const float*)d_in[7];
    const float* W3   = (const float*)d_in[8];
    const float* b3   = (const float*)d_in[9];
    float* out = (float*)d_out;

    const int IN_C = 256, HID_C = 256, OUT_C = 64;
    const int n_nodes = in_sizes[0] / IN_C;
    const int n_edges = in_sizes[1];
    const int n_pad4  = (n_nodes + 3) & ~3;
    const int nb      = (n_nodes + 1023) >> 10;   // row buckets (<= NB_MAX)

    // workspace (~168 MB), all chunks 16B-aligned
    char* wsp = (char*)d_ws;
    auto take = [&wsp](size_t bytes) {
        char* p = wsp;
        wsp += (bytes + 15) & ~(size_t)15;
        return p;
    };
    __hip_bfloat16* G  = (__hip_bfloat16*)take((size_t)n_nodes * HID_C * 2);
    __hip_bfloat16* H  = (__hip_bfloat16*)take((size_t)n_nodes * HID_C * 2);
    uint2* epk    = (uint2*)take((size_t)n_edges * 8);
    int*   srow   = (int*)take((size_t)n_edges * 4);
    uint2* epk8   = (uint2*)take((size_t)n_edges * 8);
    int*   counts = (int*)take((size_t)(n_pad4 + NB_MAX) * 4);  // counts + bcnt contiguous
    int*   bcnt   = counts + n_pad4;
    int*   gcursor= (int*)take((size_t)NB_MAX * 4);
    int*   cursor = (int*)take((size_t)n_pad4 * 4);
    int*   row_ptr= (int*)take((size_t)(n_nodes + 1) * 4);
    __hip_bfloat16* Wb1 = (__hip_bfloat16*)take((size_t)(HID_C * IN_C + HID_C * HID_C + OUT_C * HID_C) * 2);
    __hip_bfloat16* Wb2 = Wb1 + HID_C * IN_C;
    __hip_bfloat16* Wb3 = Wb2 + HID_C * HID_C;

    const dim3 blk(256);
    const int n1 = HID_C * IN_C, n2 = HID_C * HID_C, n3 = OUT_C * HID_C;
    const int cwb = ((n1 + n2 + n3) / 4 + 255) / 256;
    const int zb  = (n_pad4 + NB_MAX + 255) / 256;
    const int ebb = (n_edges + EPB - 1) / EPB;
    const int pbb = (n_edges + 255) / 256;
    const int rb  = (n_nodes + 3) / 4;            // spmm: 4 rows (waves) per block
    const int g_w = (n_nodes + 63) / 64;          // wide GEMM grid
    const int g_n = (n_nodes + 255) / 256;        // narrow GEMM grid

    // ---- weight convert + CSR build ----
    convw_kernel<<<cwb, blk, 0, stream>>>(W1, W2, W3, Wb1, n1, n2, n3);
    zero_int_kernel<<<zb, blk, 0, stream>>>(counts, n_pad4 + NB_MAX);
    hist2_kernel<<<ebb, blk, 0, stream>>>(erow, counts, bcnt, n_edges, nb);
    scan_kernel<<<1, 1024, 0, stream>>>(counts, bcnt, row_ptr, cursor, gcursor,
                                        n_nodes, n_pad4, nb);
    bin_pass_a<<<ebb, blk, 0, stream>>>(erow, ecol, eval, gcursor, srow, epk8, n_edges, nb);
    bin_pass_b<<<pbb, blk, 0, stream>>>(srow, epk8, cursor, epk, n_edges);

    // Layer 1: G = x @ W1^T + b1 ; H = relu(spmm(G))
    gemm_mfma_kernel<float><<<g_w, blk, 0, stream>>>(x, Wb1, b1, G, n_nodes, HID_C);
    spmm_csr256_kernel<true><<<rb, blk, 0, stream>>>(row_ptr, epk,
                                                     (const unsigned int*)G, H, n_nodes);

    // Layer 2: G = H @ W2^T + b2 ; H = relu(spmm(G))
    gemm_mfma_kernel<__hip_bfloat16><<<g_w, blk, 0, stream>>>(H, Wb2, b2, G, n_nodes, HID_C);
    spmm_csr256_kernel<true><<<rb, blk, 0, stream>>>(row_ptr, epk,
                                                     (const unsigned int*)G, H, n_nodes);

    // Layer 3: G[:, :64] = H @ W3^T + b3 ; out = spmm(G)
    gemm_mfma_kernel<__hip_bfloat16><<<g_n, blk, 0, stream>>>(H, Wb3, b3, G, n_nodes, OUT_C);
    spmm_csr64_kernel<<<rb, blk, 0, stream>>>(row_ptr, epk, G, out, n_nodes);
}